// Round 11
// baseline (115.255 us; speedup 1.0000x reference)
//
#include <hip/hip_runtime.h>
#include <hip/hip_bf16.h>
#include <math.h>

// ---------------------------------------------------------------------------
// VQ-VAE forward. conv1 / conv2+vq / deconv1 / deconv2 are bf16 MFMA implicit
// GEMMs. R11 = R10 with conv2vq widened to M=128 at 512 threads (8 waves):
// keeps R7's 2 waves/SIMD while halving B staging per output (R9's tile with
// R9's occupancy bug fixed).
// ws layout (bytes):
//   0          : hb/g  bf16 [32][66][66][128]                    35,684,352
//   75497472   : dq    bf16 [32][34][34][128]                     9,469,952
//   84967424   : w2p   bf16 [16 rs][128 o][128 c] PLAIN             524,288
//   85491712   : w1p   bf16 [16 m ][128 o][128 c] PLAIN             524,288
//   86016000   : Ep    bf16 [512 k][128 c]  PLAIN                   131,072
//   86147072   : w2db9 bf16 [9 de][16 col][128 c] PLAIN              36,864
//   86184192   : s2    f32  [512]                                     2,048
//   86186240   : w1b   bf16 [128 o][64 K] pre-swizzled (conv1)       16,384
// ---------------------------------------------------------------------------

typedef __attribute__((ext_vector_type(8))) short bf16x8;
typedef __attribute__((ext_vector_type(4))) float f32x4;

__device__ __forceinline__ void gload16(const void* g, const void* l) {
    __builtin_amdgcn_global_load_lds(
        (const __attribute__((address_space(1))) void*)g,
        (__attribute__((address_space(3))) void*)l, 16, 0, 0);
}

// 16B fragment offset in swizzled [*][128c] bf16 tile (256B rows)
__device__ __forceinline__ int fragoff(int row, int ks, int lane) {
    return (row << 8) + (((ks << 6) + (lane & 0x30)) ^ ((row & 7) << 4));
}
// 16B fragment offset in swizzled [*][64c] bf16 tile (128B rows), ks in {0,1}
__device__ __forceinline__ int fragoff64(int row, int ks, int lane) {
    return (row << 7) + (((ks << 6) + (lane & 0x30)) ^ ((row & 7) << 4));
}

// ---- k_init: border fills (vectorized x8) + weight/codebook prep ----
__global__ __launch_bounds__(256) void k_init(
    const float* __restrict__ ew1, const float* __restrict__ ew2,
    const float* __restrict__ E,   const float* __restrict__ dw1,
    const float* __restrict__ dw2,
    __hip_bfloat16* __restrict__ hb,  __hip_bfloat16* __restrict__ w2p,
    __hip_bfloat16* __restrict__ w1p, __hip_bfloat16* __restrict__ Ep,
    __hip_bfloat16* __restrict__ w1b, __hip_bfloat16* __restrict__ w2db9,
    __hip_bfloat16* __restrict__ dq,  float* __restrict__ s2)
{
    int bid = blockIdx.x, t = threadIdx.x;
    bf16x8 zero8 = {0, 0, 0, 0, 0, 0, 0, 0};
    if (bid < 520) {                                // hb/g border ring, 8 c/thread
        int vid = bid * 256 + t;                    // 133,120
        const int NROWV = 67584;
        if (vid < NROWV) {
            int c8 = (vid & 15) << 3;
            int xx = (vid >> 4) % 66;
            int r2 = vid / (66 * 16);
            int yy = (r2 & 1) * 65;
            int n = r2 >> 1;
            *(bf16x8*)&hb[((n * 66 + yy) * 66 + xx) * 128 + c8] = zero8;
        } else {
            int v2 = vid - NROWV;
            int c8 = (v2 & 15) << 3;
            int xs = (v2 >> 4) & 1;
            int yy = ((v2 >> 5) & 63) + 1;
            int n = v2 >> 11;
            *(bf16x8*)&hb[((n * 66 + yy) * 66 + xs * 65) * 128 + c8] = zero8;
        }
    } else if (bid < 1544) {                        // w2p plain [rs][o][c]
        int tid = (bid - 520) * 256 + t;            // 262144
        int c = tid & 127, o = (tid >> 7) & 127, rs = tid >> 14;
        int r = rs >> 2, s = rs & 3;
        w2p[tid] = __float2bfloat16(ew2[((o * 128 + c) * 4 + r) * 4 + s]);
    } else if (bid < 2568) {                        // w1p plain [m][o][c]
        int tid = (bid - 1544) * 256 + t;           // 262144
        int c = tid & 127, o = (tid >> 7) & 127, m = tid >> 14;
        int pe = (m >> 3) & 1, qe = (m >> 2) & 1, tt = (m >> 1) & 1, u = m & 1;
        w1p[tid] = __float2bfloat16(dw1[((o * 128 + c) * 4 + (pe + 2 * tt)) * 4 + (qe + 2 * u)]);
    } else if (bid < 2824) {                        // Ep plain [k][c]
        int tid = (bid - 2568) * 256 + t;           // 65536
        Ep[tid] = __float2bfloat16(E[tid]);
    } else if (bid < 2856) {                        // w1b (conv1, pre-swizzled, K pad 48->64)
        int tid = (bid - 2824) * 256 + t;           // 8192
        int o = tid >> 6, cpos = tid & 63;
        int slot = cpos >> 3, e = cpos & 7;
        int k = ((slot ^ (o & 7)) << 3) | e;
        float v = 0.f;
        if (k < 48) {
            int c = k >> 4, r = (k >> 2) & 3, s = k & 3;
            v = ew1[((o * 3 + c) * 4 + r) * 4 + s];
        }
        w1b[tid] = __float2bfloat16(v);
    } else if (bid < 2928) {                        // w2db9 plain [9 de][16 col][128 c]
        int tid = (bid - 2856) * 256 + t;           // 18432
        int c = tid & 127;
        int col = (tid >> 7) & 15;
        int de = tid >> 11;                         // 0..8
        int o = col & 3, pq = col >> 2;
        int d = de / 3, e_ = de - d * 3;
        int pe = pq >> 1, qe = pq & 1;
        int tt = d - pe, u = e_ - qe;
        float v = 0.f;
        if (o < 3 && tt >= 0 && tt < 2 && u >= 0 && u < 2)
            v = dw2[((o * 128 + c) * 4 + (pe + 2 * tt)) * 4 + (qe + 2 * u)];
        w2db9[tid] = __float2bfloat16(v);
    } else if (bid < 2930) {                        // sumE2
        int k = (bid - 2928) * 256 + t;             // 512
        float a = 0.f;
        const float* e = E + k * 128;
        for (int c = 0; c < 128; ++c) a = fmaf(e[c], e[c], a);
        s2[k] = a;
    } else {                                        // dq border ring, 8 c/thread
        int vid = (bid - 2930) * 256 + t;           // 67,584
        int n = vid / 2112;
        int rem = vid - n * 2112;
        int c8 = (rem & 15) << 3;
        int pp = rem >> 4;
        int yy, xx;
        if (pp < 68) { yy = (pp >= 34) ? 33 : 0; xx = pp % 34; }
        else { int q = pp - 68; yy = 1 + (q >> 1); xx = (q & 1) * 33; }
        *(bf16x8*)&dq[((n * 34 + yy) * 34 + xx) * 128 + c8] = zero8;
    }
}

// ---- conv1 as MFMA implicit GEMM; x-window staged to LDS via 9 gload16 ----
__global__ __launch_bounds__(256) void k_conv1g(
    const float* __restrict__ x, const __hip_bfloat16* __restrict__ w1b,
    const float* __restrict__ b1, __hip_bfloat16* __restrict__ hb)
{
    __shared__ char smem[41984];                    // A 16K | B 16K | xw 9216
    int t = threadIdx.x, lane = t & 63, w = t >> 6;
    int wr = w >> 1, wc = w & 1;
    int bid0 = blockIdx.x;                          // 1024
    int bid = ((bid0 & 7) << 7) | (bid0 >> 3);      // XCD swizzle
    int posbase = bid << 7;
    int ng = posbase >> 12, p0g = (posbase >> 6) & 63;

    #pragma unroll
    for (int i = 0; i < 4; ++i)
        gload16(w1b + ((w * 4 + i) * 512 + lane * 8), &smem[16384 + ((w * 4 + i) << 10)]);

    #pragma unroll
    for (int k3 = 0; k3 < 3; ++k3) {
        int j = w + (k3 << 2);
        if (j < 9) {
            int wrow = (j << 1) | (lane >> 5);
            int c = wrow / 6, yy = wrow - c * 6;
            int y = 2 * p0g - 1 + yy;
            int ysrc = y < 0 ? 0 : (y > 127 ? 127 : y);
            gload16(x + (((ng * 3 + c) * 128 + ysrc) << 7) + ((lane & 31) << 2),
                    &smem[32768 + (j << 10)]);
        }
    }
    __syncthreads();

    {
        int row = t >> 1, half = t & 1;
        int pl = row >> 6, q = row & 63;
        #pragma unroll
        for (int j = 0; j < 4; ++j) {
            int d = half * 4 + j;
            int sct = d ^ (row & 7);
            __hip_bfloat16 hv[8];
            #pragma unroll
            for (int e = 0; e < 8; ++e) {
                int k = sct * 8 + e;
                float v = 0.f;
                if (k < 48) {
                    int c = k >> 4, r = (k >> 2) & 3, s4 = k & 3;
                    int y = 2 * (p0g + pl) + r - 1;
                    int xg = 2 * q + s4 - 1;
                    if (((unsigned)y < 128u) && ((unsigned)xg < 128u)) {
                        int wrow = c * 6 + 2 * pl + r;
                        v = *(const float*)&smem[32768 + (wrow << 9) + (xg << 2)];
                    }
                }
                hv[e] = __float2bfloat16(v);
            }
            *(bf16x8*)&smem[(row << 7) + d * 16] = *(bf16x8*)hv;
        }
    }
    __syncthreads();

    f32x4 acc[4][4];
    #pragma unroll
    for (int mi = 0; mi < 4; ++mi)
        #pragma unroll
        for (int ni = 0; ni < 4; ++ni) acc[mi][ni] = (f32x4){0.f, 0.f, 0.f, 0.f};

    #pragma unroll
    for (int ks = 0; ks < 2; ++ks) {
        bf16x8 av[4], bv[4];
        #pragma unroll
        for (int mi = 0; mi < 4; ++mi)
            av[mi] = *(const bf16x8*)&smem[fragoff64((wr << 6) + (mi << 4) + (lane & 15), ks, lane)];
        #pragma unroll
        for (int ni = 0; ni < 4; ++ni)
            bv[ni] = *(const bf16x8*)&smem[16384 + fragoff64((wc << 6) + (ni << 4) + (lane & 15), ks, lane)];
        #pragma unroll
        for (int mi = 0; mi < 4; ++mi)
            #pragma unroll
            for (int ni = 0; ni < 4; ++ni)
                acc[mi][ni] = __builtin_amdgcn_mfma_f32_16x16x32_bf16(av[mi], bv[ni], acc[mi][ni], 0, 0, 0);
    }

    int rg = (lane >> 4) << 2;
    #pragma unroll
    for (int mi = 0; mi < 4; ++mi)
        #pragma unroll
        for (int ni = 0; ni < 4; ++ni) {
            int o = (wc << 6) + (ni << 4) + (lane & 15);
            float bias = b1[o];
            #pragma unroll
            for (int j = 0; j < 4; ++j) {
                int rowg = posbase + (wr << 6) + (mi << 4) + rg + j;
                int n = rowg >> 12, p = (rowg >> 6) & 63, q = rowg & 63;
                float v = acc[mi][ni][j] + bias;
                v = v > 0.f ? v : 0.f;
                hb[((n * 66 + p + 1) * 66 + q + 1) * 128 + o] = __float2bfloat16(v);
            }
        }
}

// ---- conv2 + VQ fused, M=128, 8 waves (512 thr), BK=64, prefetch-dbuf ----
__global__ __launch_bounds__(512) void k_conv2vq(
    const __hip_bfloat16* __restrict__ hb, const __hip_bfloat16* __restrict__ w2p,
    const float* __restrict__ b2, const __hip_bfloat16* __restrict__ Ep,
    const float* __restrict__ s2, __hip_bfloat16* __restrict__ dq)
{
    __shared__ char smem[65536];                // buf b at b*32768: A 16K | B 16K
    int t = threadIdx.x, lane = t & 63, w = t >> 6;     // w 0..7
    int wr = w >> 2, wc = w & 3;
    int bid0 = blockIdx.x;                      // 256
    int bid = ((bid0 & 7) << 5) | (bid0 >> 3);  // XCD swizzle
    int posbase = bid << 7;                     // 128 rows
    int n = posbase >> 10, p0 = (posbase >> 5) & 31;

    int aoff[2], boff[2];
    #pragma unroll
    for (int i = 0; i < 2; ++i) {
        int r = ((w << 1) + i) * 8 + (lane >> 3);
        int slot = lane & 7;
        int p = p0 + (r >> 5), q = r & 31;
        int csw = (slot ^ (r & 7)) << 3;
        aoff[i] = (((n * 66 + 2 * p) * 66 + 2 * q) << 7) + csw;
        boff[i] = (r << 7) + csw;               // B row o == r pattern
    }

#define C2_STAGE(STEP, BASE) { \
    int rs_ = (STEP) >> 1, ch_ = (STEP) & 1; \
    int aadd_ = ((((rs_ >> 2) * 66) + (rs_ & 3)) << 7) + (ch_ << 6); \
    int badd_ = (rs_ << 14) + (ch_ << 6); \
    _Pragma("unroll") \
    for (int i = 0; i < 2; ++i) { \
        gload16(hb + aoff[i] + aadd_, &smem[(BASE) + (((w << 1) + i) << 10)]); \
        gload16(w2p + boff[i] + badd_, &smem[(BASE) + 16384 + (((w << 1) + i) << 10)]); \
    } }

    f32x4 acc[4][2];
    #pragma unroll
    for (int mi = 0; mi < 4; ++mi)
        #pragma unroll
        for (int ni = 0; ni < 2; ++ni) acc[mi][ni] = (f32x4){0.f, 0.f, 0.f, 0.f};

    C2_STAGE(0, 0);
    __syncthreads();
    for (int step = 0; step < 32; ++step) {
        int cb = (step & 1) * 32768;
        if (step < 31) C2_STAGE(step + 1, ((step + 1) & 1) * 32768);
        #pragma unroll
        for (int ks = 0; ks < 2; ++ks) {
            bf16x8 av[4], bv[2];
            #pragma unroll
            for (int mi = 0; mi < 4; ++mi)
                av[mi] = *(const bf16x8*)&smem[cb + fragoff64((wr << 6) + (mi << 4) + (lane & 15), ks, lane)];
            #pragma unroll
            for (int ni = 0; ni < 2; ++ni)
                bv[ni] = *(const bf16x8*)&smem[cb + 16384 + fragoff64((wc << 5) + (ni << 4) + (lane & 15), ks, lane)];
            #pragma unroll
            for (int mi = 0; mi < 4; ++mi)
                #pragma unroll
                for (int ni = 0; ni < 2; ++ni)
                    acc[mi][ni] = __builtin_amdgcn_mfma_f32_16x16x32_bf16(av[mi], bv[ni], acc[mi][ni], 0, 0, 0);
        }
        __syncthreads();
    }

#define VQ_STAGE(CHUNK, BASE) { \
    _Pragma("unroll") \
    for (int i = 0; i < 2; ++i) { \
        int kl_ = (((w << 1) + i) << 2) + (lane >> 4); \
        gload16(Ep + ((((CHUNK) << 6) + kl_) << 7) + (((lane & 15) ^ (kl_ & 7)) << 3), \
                &smem[(BASE) + (((w << 1) + i) << 10)]); \
    } }

    // write z (bias + bf16) into LDS [128 r][128 c] at [0,32K); prefetch E chunk 0
    {
        int rg = (lane >> 4) << 2;
        #pragma unroll
        for (int mi = 0; mi < 4; ++mi)
            #pragma unroll
            for (int ni = 0; ni < 2; ++ni) {
                int o = (wc << 5) + (ni << 4) + (lane & 15);
                float bias = b2[o];
                #pragma unroll
                for (int j = 0; j < 4; ++j) {
                    int r = (wr << 6) + (mi << 4) + rg + j;
                    int byteoff = (r << 8) + (((((o >> 3) ^ (r & 7))) << 4) | ((o & 7) << 1));
                    __hip_bfloat16 hv = __float2bfloat16(acc[mi][ni][j] + bias);
                    *(__hip_bfloat16*)&smem[byteoff] = hv;
                }
            }
    }
    VQ_STAGE(0, 32768);
    __syncthreads();

    // VQ: 8 chunks of 64 codes; wave (wr,wc): rows wr*64+mi*16, cols wc*16
    float bvv[4][4];
    int   bii[4][4];
    #pragma unroll
    for (int mi = 0; mi < 4; ++mi)
        #pragma unroll
        for (int j = 0; j < 4; ++j) { bvv[mi][j] = 3.4e38f; bii[mi][j] = 0; }

    for (int chunk = 0; chunk < 8; ++chunk) {
        int eb = 32768 + ((chunk & 1) << 14);
        if (chunk < 7) VQ_STAGE(chunk + 1, 32768 + (((chunk + 1) & 1) << 14));
        f32x4 a2[4];
        #pragma unroll
        for (int mi = 0; mi < 4; ++mi) a2[mi] = (f32x4){0.f, 0.f, 0.f, 0.f};
        #pragma unroll
        for (int ks = 0; ks < 4; ++ks) {
            bf16x8 bv = *(const bf16x8*)&smem[eb + fragoff((wc << 4) + (lane & 15), ks, lane)];
            #pragma unroll
            for (int mi = 0; mi < 4; ++mi) {
                bf16x8 av = *(const bf16x8*)&smem[fragoff((wr << 6) + (mi << 4) + (lane & 15), ks, lane)];
                a2[mi] = __builtin_amdgcn_mfma_f32_16x16x32_bf16(av, bv, a2[mi], 0, 0, 0);
            }
        }
        int kg = (chunk << 6) + (wc << 4) + (lane & 15);
        float s2v = s2[kg];
        #pragma unroll
        for (int mi = 0; mi < 4; ++mi)
            #pragma unroll
            for (int j = 0; j < 4; ++j) {
                float sc = s2v - 2.f * a2[mi][j];
                if (sc < bvv[mi][j]) { bvv[mi][j] = sc; bii[mi][j] = kg; }
            }
        __syncthreads();
    }

    // cross-wave reduction: 4 candidates per row (wc 0..3)
    float* redv  = (float*)&smem[32768];
    int*   redi  = (int*)&smem[32768 + 2048];
    int*   idx_l = (int*)&smem[32768 + 4096];
    #pragma unroll
    for (int mi = 0; mi < 4; ++mi)
        #pragma unroll
        for (int j = 0; j < 4; ++j) {
            float v = bvv[mi][j];
            int   ix = bii[mi][j];
            #pragma unroll
            for (int m = 1; m < 16; m <<= 1) {
                float ov = __shfl_xor(v, m, 64);
                int   oi = __shfl_xor(ix, m, 64);
                if (ov < v || (ov == v && oi < ix)) { v = ov; ix = oi; }
            }
            if ((lane & 15) == 0) {
                int r = (wr << 6) + (mi << 4) + ((lane >> 4) << 2) + j;
                redv[(r << 2) + wc] = v;
                redi[(r << 2) + wc] = ix;
            }
        }
    __syncthreads();
    if (t < 128) {
        float bv_ = redv[t << 2];
        int   bi_ = redi[t << 2];
        #pragma unroll
        for (int w2 = 1; w2 < 4; ++w2) {
            float ov = redv[(t << 2) + w2];
            int   oi = redi[(t << 2) + w2];
            if (ov < bv_ || (ov == bv_ && oi < bi_)) { bv_ = ov; bi_ = oi; }
        }
        idx_l[t] = bi_;
    }
    __syncthreads();

    // stage selected codebook rows (bf16) into [0,32K): [128 r][128 c] linear
    #pragma unroll
    for (int i = 0; i < 4; ++i) {
        int idx2 = (w << 2) + i;                // 0..31
        int r = (idx2 << 2) + (lane >> 4);      // 0..127
        int krow = idx_l[r];
        gload16(Ep + ((krow << 7) + ((lane & 15) << 3)), &smem[idx2 << 10]);
    }
    __syncthreads();

    // scatter: 128 rows = image n, channels [cd0,cd0+16), all 1024 positions
    int cd0 = (posbase >> 3) & 127;
    const unsigned short* eb2p = (const unsigned short*)smem;
    #pragma unroll
    for (int k2 = 0; k2 < 2; ++k2) {
        int sp = (k2 << 9) + t;                 // 0..1023
        int hi = sp >> 7, lo = sp & 127;
        int y = hi * 4 + (lo >> 5), xx = lo & 31;
        unsigned short vals[16];
        #pragma unroll
        for (int ci = 0; ci < 16; ++ci)
            vals[ci] = eb2p[(((ci << 3) | hi) << 7) + lo];
        __hip_bfloat16* dst = dq + ((n * 34 + y + 1) * 34 + (xx + 1)) * 128 + cd0;
        *(bf16x8*)dst = *(bf16x8*)&vals[0];
        *(bf16x8*)(dst + 8) = *(bf16x8*)&vals[8];
    }
}

// ---- deconv1, prefetch-dbuf: M=128, BK=64, 8 steps, 1 barrier/step ----
__global__ __launch_bounds__(256) void k_deconv1(
    const __hip_bfloat16* __restrict__ dq, const __hip_bfloat16* __restrict__ w1p,
    const float* __restrict__ b1, __hip_bfloat16* __restrict__ g)
{
    __shared__ char smem[65536];                // buf b at b*32768: A 16K | B 16K
    int t = threadIdx.x, lane = t & 63, w = t >> 6;
    int wr = w >> 1, wc = w & 1;
    int bid0 = blockIdx.x;                      // 1024
    int bid = ((bid0 & 7) << 7) | (bid0 >> 3);  // XCD swizzle
    int ag = bid & 7, qe = (bid >> 3) & 1, pe = (bid >> 4) & 1, n = bid >> 5;

    int aoff[4], boff[4];
    #pragma unroll
    for (int i = 0; i < 4; ++i) {
        int r = ((w << 2) + i) * 8 + (lane >> 3);
        int slot = lane & 7;
        int a = (ag << 2) + (r >> 5), b = r & 31;
        aoff[i] = (((n * 34 + (a + pe)) * 34 + (b + qe)) << 7) + ((slot ^ (r & 7)) << 3);
        boff[i] = (r << 7) + ((slot ^ (r & 7)) << 3);
    }
    int mbase = (pe << 3) | (qe << 2);

#define D1_STAGE(STEP, BASE) { \
    int tu_ = (STEP) >> 1, ch_ = (STEP) & 1; \
    int tt_ = tu_ >> 1, u_ = tu_ & 1; \
    int aadd_ = ((tt_ * 34 + u_) << 7) + (ch_ << 6); \
    int badd_ = ((mbase + tu_) << 14) + (ch_ << 6); \
    _Pragma("unroll") \
    for (int i = 0; i < 4; ++i) { \
        gload16(dq + aoff[i] + aadd_, &smem[(BASE) + (((w << 2) + i) << 10)]); \
        gload16(w1p + boff[i] + badd_, &smem[(BASE) + 16384 + (((w << 2) + i) << 10)]); \
    } }

    f32x4 acc[4][4];
    #pragma unroll
    for (int mi = 0; mi < 4; ++mi)
        #pragma unroll
        for (int ni = 0; ni < 4; ++ni) acc[mi][ni] = (f32x4){0.f, 0.f, 0.f, 0.f};

    D1_STAGE(0, 0);
    __syncthreads();
    for (int step = 0; step < 8; ++step) {
        int cb = (step & 1) * 32768;
        if (step < 7) D1_STAGE(step + 1, ((step + 1) & 1) * 32768);
        #pragma unroll
        for (int ks = 0; ks < 2; ++ks) {
            bf16x8 av[4], bv[4];
            #pragma unroll
            for (int mi = 0; mi < 4; ++mi)
                av[mi] = *(const bf16x8*)&smem[cb + fragoff64((wr << 6) + (mi << 4) + (lane & 15), ks, lane)];
            #pragma unroll
            for (int ni = 0; ni < 4; ++ni)
                bv[ni] = *(const bf16x8*)&smem[cb + 16384 + fragoff64((wc << 6) + (ni << 4) + (lane & 15), ks, lane)];
            #pragma unroll
            for (int mi = 0; mi < 4; ++mi)
                #pragma unroll
                for (int ni = 0; ni < 4; ++ni)
                    acc[mi][ni] = __builtin_amdgcn_mfma_f32_16x16x32_bf16(av[mi], bv[ni], acc[mi][ni], 0, 0, 0);
        }
        __syncthreads();
    }

    int rg = (lane >> 4) << 2;
    #pragma unroll
    for (int mi = 0; mi < 4; ++mi)
        #pragma unroll
        for (int ni = 0; ni < 4; ++ni) {
            int o = (wc << 6) + (ni << 4) + (lane & 15);
            float bias = b1[o];
            #pragma unroll
            for (int j = 0; j < 4; ++j) {
                int row = (wr << 6) + (mi << 4) + rg + j;
                int a = (ag << 2) + (row >> 5), b = row & 31;
                int y = 2 * a + pe, xx2 = 2 * b + qe;
                float v = acc[mi][ni][j] + bias;
                v = v > 0.f ? v : 0.f;
                g[((n * 66 + y + 1) * 66 + xx2 + 1) * 128 + o] = __float2bfloat16(v);
            }
        }
}

// ---- deconv2, 9-neighbor, prefetch-dbuf: BK=64, 18 steps, 1 barrier/step ----
__global__ __launch_bounds__(256) void k_deconv2g(
    const __hip_bfloat16* __restrict__ g, const __hip_bfloat16* __restrict__ w2db9,
    const float* __restrict__ b2, float* __restrict__ out)
{
    __shared__ char smem[36864];                // buf b at b*18432: A 16K | B 2K
    int t = threadIdx.x, lane = t & 63, w = t >> 6;
    int bid0 = blockIdx.x;                      // 1024
    int bid = ((bid0 & 7) << 7) | (bid0 >> 3);  // XCD swizzle
    int atile = bid & 31, n = bid >> 5;
    int a0 = atile << 1;

    int aoff[4];
    #pragma unroll
    for (int i = 0; i < 4; ++i) {
        int r = ((w << 2) + i) * 8 + (lane >> 3);
        int al = r >> 6, b = r & 63;
        aoff[i] = (((n * 66 + (a0 + al)) * 66 + b) << 7) + (((lane & 7) ^ (r & 7)) << 3);
    }

#define D2_STAGE(STEP, BASE) { \
    int de_ = (STEP) >> 1, ch_ = (STEP) & 1; \
    int dy_ = de_ / 3, dx_ = de_ - dy_ * 3; \
    int aadd_ = ((dy_ * 66 + dx_) << 7) + (ch_ << 6); \
    _Pragma("unroll") \
    for (int i = 0; i < 4; ++i) \
        gload16(g + aoff[i] + aadd_, &smem[(BASE) + (((w << 2) + i) << 10)]); \
    if (w < 2) { \
        int kl_ = (w << 3) + (lane >> 3); \
        gload16(w2db9 + (de_ << 11) + (kl_ << 7) + (ch_ << 6) + (((lane & 7) ^ (kl_ & 7)) << 3), \
                &smem[(BASE) + 16384 + (w << 10)]); \
    } }

    f32x4 acc[2];
    acc[0] = (f32x4){0.f, 0.f, 0.f, 0.f};
    acc[1] = (f32x4){0.f, 0.f, 0.f, 0.f};

    D2_STAGE(0, 0);
    __syncthreads();
    for (int step = 0; step < 18; ++step) {
        int cb = (step & 1) * 18432;
        if (step < 17) D2_STAGE(step + 1, ((step + 1) & 1) * 18432);
        #pragma unroll
        for (int ks = 0; ks < 2; ++ks) {
            bf16x8 av[2], bv;
            #pragma unroll
            for (int mi = 0; mi < 2; ++mi)
                av[mi] = *(const bf16x8*)&smem[cb + fragoff64((w << 5) + (mi << 4) + (lane & 15), ks, lane)];
            bv = *(const bf16x8*)&smem[cb + 16384 + fragoff64(lane & 15, ks, lane)];
            #pragma unroll
            for (int mi = 0; mi < 2; ++mi)
                acc[mi] = __builtin_amdgcn_mfma_f32_16x16x32_bf16(av[mi], bv, acc[mi], 0, 0, 0);
        }
        __syncthreads();
    }

    int rg = (lane >> 4) << 2;
    int col = lane & 15, o = col & 3, pq = col >> 2;
    if (o < 3) {
        int pe = pq >> 1, qe = pq & 1;
        float bias = b2[o];
        #pragma unroll
        for (int mi = 0; mi < 2; ++mi)
            #pragma unroll
            for (int j = 0; j < 4; ++j) {
                int row = (w << 5) + (mi << 4) + rg + j;
                int y = 2 * (a0 + (row >> 6)) + pe;
                int x = 2 * (row & 63) + qe;
                float v = acc[mi][j] + bias;
                out[((n * 3 + o) * 128 + y) * 128 + x] = 1.f / (1.f + expf(-v));
            }
    }
}

extern "C" void kernel_launch(void* const* d_in, const int* in_sizes, int n_in,
                              void* d_out, int out_size, void* d_ws, size_t ws_size,
                              hipStream_t stream) {
    const float* x   = (const float*)d_in[0];
    const float* ew1 = (const float*)d_in[1];
    const float* eb1 = (const float*)d_in[2];
    const float* ew2 = (const float*)d_in[3];
    const float* eb2 = (const float*)d_in[4];
    const float* E   = (const float*)d_in[5];
    const float* dw1 = (const float*)d_in[6];
    const float* db1 = (const float*)d_in[7];
    const float* dw2 = (const float*)d_in[8];
    const float* db2 = (const float*)d_in[9];
    float* out = (float*)d_out;

    char* W = (char*)d_ws;
    __hip_bfloat16* hb    = (__hip_bfloat16*)(W + 0);
    __hip_bfloat16* g     = (__hip_bfloat16*)(W + 0);  // union: hb dead after conv2
    __hip_bfloat16* dq    = (__hip_bfloat16*)(W + 75497472);
    __hip_bfloat16* w2p   = (__hip_bfloat16*)(W + 84967424);
    __hip_bfloat16* w1p   = (__hip_bfloat16*)(W + 85491712);
    __hip_bfloat16* Ep    = (__hip_bfloat16*)(W + 86016000);
    __hip_bfloat16* w2db9 = (__hip_bfloat16*)(W + 86147072);
    float*          s2    = (float*)(W + 86184192);
    __hip_bfloat16* w1b   = (__hip_bfloat16*)(W + 86186240);

    k_init    <<<3194, 256, 0, stream>>>(ew1, ew2, E, dw1, dw2,
                                         hb, w2p, w1p, Ep, w1b, w2db9, dq, s2);
    k_conv1g  <<<1024, 256, 0, stream>>>(x, w1b, eb1, hb);
    k_conv2vq <<<256,  512, 0, stream>>>(hb, w2p, eb2, Ep, s2, dq);
    k_deconv1 <<<1024, 256, 0, stream>>>(dq, w1p, db1, g);
    k_deconv2g<<<1024, 256, 0, stream>>>(g, w2db9, db2, out);
}

// Round 12
// 111.853 us; speedup vs baseline: 1.0304x; 1.0304x over previous
//
#include <hip/hip_runtime.h>
#include <hip/hip_bf16.h>
#include <math.h>

// ---------------------------------------------------------------------------
// VQ-VAE forward. conv1 / conv2+vq / deconv1 / deconv2 are bf16 MFMA implicit
// GEMMs. R12 = R10 byte-identical revert (best measured: 112.2us).
// All K-loops: prefetch double-buffered staging (issue next tile's
// global_load_lds BEFORE computing current tile; ONE barrier per step).
// ws layout (bytes):
//   0          : hb/g  bf16 [32][66][66][128]                    35,684,352
//   75497472   : dq    bf16 [32][34][34][128]                     9,469,952
//   84967424   : w2p   bf16 [16 rs][128 o][128 c] PLAIN             524,288
//   85491712   : w1p   bf16 [16 m ][128 o][128 c] PLAIN             524,288
//   86016000   : Ep    bf16 [512 k][128 c]  PLAIN                   131,072
//   86147072   : w2db9 bf16 [9 de][16 col][128 c] PLAIN              36,864
//   86184192   : s2    f32  [512]                                     2,048
//   86186240   : w1b   bf16 [128 o][64 K] pre-swizzled (conv1)       16,384
// ---------------------------------------------------------------------------

typedef __attribute__((ext_vector_type(8))) short bf16x8;
typedef __attribute__((ext_vector_type(4))) float f32x4;

__device__ __forceinline__ void gload16(const void* g, const void* l) {
    __builtin_amdgcn_global_load_lds(
        (const __attribute__((address_space(1))) void*)g,
        (__attribute__((address_space(3))) void*)l, 16, 0, 0);
}

// 16B fragment offset in swizzled [*][128c] bf16 tile (256B rows)
__device__ __forceinline__ int fragoff(int row, int ks, int lane) {
    return (row << 8) + (((ks << 6) + (lane & 0x30)) ^ ((row & 7) << 4));
}
// 16B fragment offset in swizzled [*][64c] bf16 tile (128B rows), ks in {0,1}
__device__ __forceinline__ int fragoff64(int row, int ks, int lane) {
    return (row << 7) + (((ks << 6) + (lane & 0x30)) ^ ((row & 7) << 4));
}

// ---- k_init: border fills (vectorized x8) + weight/codebook prep ----
// grid 3194: [0,520) hb border | [520,1544) w2p | [1544,2568) w1p |
// [2568,2824) Ep | [2824,2856) w1b | [2856,2928) w2db9 | [2928,2930) s2 |
// [2930,3194) dq border
__global__ __launch_bounds__(256) void k_init(
    const float* __restrict__ ew1, const float* __restrict__ ew2,
    const float* __restrict__ E,   const float* __restrict__ dw1,
    const float* __restrict__ dw2,
    __hip_bfloat16* __restrict__ hb,  __hip_bfloat16* __restrict__ w2p,
    __hip_bfloat16* __restrict__ w1p, __hip_bfloat16* __restrict__ Ep,
    __hip_bfloat16* __restrict__ w1b, __hip_bfloat16* __restrict__ w2db9,
    __hip_bfloat16* __restrict__ dq,  float* __restrict__ s2)
{
    int bid = blockIdx.x, t = threadIdx.x;
    bf16x8 zero8 = {0, 0, 0, 0, 0, 0, 0, 0};
    if (bid < 520) {                                // hb/g border ring, 8 c/thread
        int vid = bid * 256 + t;                    // 133,120
        const int NROWV = 67584;                    // rows y=0,65: 64*(66*16)
        if (vid < NROWV) {
            int c8 = (vid & 15) << 3;
            int xx = (vid >> 4) % 66;
            int r2 = vid / (66 * 16);
            int yy = (r2 & 1) * 65;
            int n = r2 >> 1;
            *(bf16x8*)&hb[((n * 66 + yy) * 66 + xx) * 128 + c8] = zero8;
        } else {
            int v2 = vid - NROWV;                   // cols x=0,65: 65,536
            int c8 = (v2 & 15) << 3;
            int xs = (v2 >> 4) & 1;
            int yy = ((v2 >> 5) & 63) + 1;
            int n = v2 >> 11;
            *(bf16x8*)&hb[((n * 66 + yy) * 66 + xs * 65) * 128 + c8] = zero8;
        }
    } else if (bid < 1544) {                        // w2p plain [rs][o][c]
        int tid = (bid - 520) * 256 + t;            // 262144
        int c = tid & 127, o = (tid >> 7) & 127, rs = tid >> 14;
        int r = rs >> 2, s = rs & 3;
        w2p[tid] = __float2bfloat16(ew2[((o * 128 + c) * 4 + r) * 4 + s]);
    } else if (bid < 2568) {                        // w1p plain [m][o][c]
        int tid = (bid - 1544) * 256 + t;           // 262144
        int c = tid & 127, o = (tid >> 7) & 127, m = tid >> 14;
        int pe = (m >> 3) & 1, qe = (m >> 2) & 1, tt = (m >> 1) & 1, u = m & 1;
        w1p[tid] = __float2bfloat16(dw1[((o * 128 + c) * 4 + (pe + 2 * tt)) * 4 + (qe + 2 * u)]);
    } else if (bid < 2824) {                        // Ep plain [k][c]
        int tid = (bid - 2568) * 256 + t;           // 65536
        Ep[tid] = __float2bfloat16(E[tid]);
    } else if (bid < 2856) {                        // w1b (conv1, pre-swizzled, K pad 48->64)
        int tid = (bid - 2824) * 256 + t;           // 8192
        int o = tid >> 6, cpos = tid & 63;
        int slot = cpos >> 3, e = cpos & 7;
        int k = ((slot ^ (o & 7)) << 3) | e;
        float v = 0.f;
        if (k < 48) {
            int c = k >> 4, r = (k >> 2) & 3, s = k & 3;
            v = ew1[((o * 3 + c) * 4 + r) * 4 + s];
        }
        w1b[tid] = __float2bfloat16(v);
    } else if (bid < 2928) {                        // w2db9 plain [9 de][16 col][128 c]
        int tid = (bid - 2856) * 256 + t;           // 18432
        int c = tid & 127;
        int col = (tid >> 7) & 15;
        int de = tid >> 11;                         // 0..8
        int o = col & 3, pq = col >> 2;
        int d = de / 3, e_ = de - d * 3;
        int pe = pq >> 1, qe = pq & 1;
        int tt = d - pe, u = e_ - qe;
        float v = 0.f;
        if (o < 3 && tt >= 0 && tt < 2 && u >= 0 && u < 2)
            v = dw2[((o * 128 + c) * 4 + (pe + 2 * tt)) * 4 + (qe + 2 * u)];
        w2db9[tid] = __float2bfloat16(v);
    } else if (bid < 2930) {                        // sumE2
        int k = (bid - 2928) * 256 + t;             // 512
        float a = 0.f;
        const float* e = E + k * 128;
        for (int c = 0; c < 128; ++c) a = fmaf(e[c], e[c], a);
        s2[k] = a;
    } else {                                        // dq border ring, 8 c/thread
        int vid = (bid - 2930) * 256 + t;           // 67,584
        int n = vid / 2112;
        int rem = vid - n * 2112;
        int c8 = (rem & 15) << 3;
        int pp = rem >> 4;                          // 0..131
        int yy, xx;
        if (pp < 68) { yy = (pp >= 34) ? 33 : 0; xx = pp % 34; }
        else { int q = pp - 68; yy = 1 + (q >> 1); xx = (q & 1) * 33; }
        *(bf16x8*)&dq[((n * 34 + yy) * 34 + xx) * 128 + c8] = zero8;
    }
}

// ---- conv1 as MFMA implicit GEMM; x-window staged to LDS via 9 gload16 ----
__global__ __launch_bounds__(256) void k_conv1g(
    const float* __restrict__ x, const __hip_bfloat16* __restrict__ w1b,
    const float* __restrict__ b1, __hip_bfloat16* __restrict__ hb)
{
    __shared__ char smem[41984];                    // A 16K | B 16K | xw 9216
    int t = threadIdx.x, lane = t & 63, w = t >> 6;
    int wr = w >> 1, wc = w & 1;
    int bid0 = blockIdx.x;                          // 1024
    int bid = ((bid0 & 7) << 7) | (bid0 >> 3);      // XCD swizzle
    int posbase = bid << 7;
    int ng = posbase >> 12, p0g = (posbase >> 6) & 63;

    #pragma unroll
    for (int i = 0; i < 4; ++i)
        gload16(w1b + ((w * 4 + i) * 512 + lane * 8), &smem[16384 + ((w * 4 + i) << 10)]);

    #pragma unroll
    for (int k3 = 0; k3 < 3; ++k3) {
        int j = w + (k3 << 2);
        if (j < 9) {
            int wrow = (j << 1) | (lane >> 5);
            int c = wrow / 6, yy = wrow - c * 6;
            int y = 2 * p0g - 1 + yy;
            int ysrc = y < 0 ? 0 : (y > 127 ? 127 : y);
            gload16(x + (((ng * 3 + c) * 128 + ysrc) << 7) + ((lane & 31) << 2),
                    &smem[32768 + (j << 10)]);
        }
    }
    __syncthreads();

    {
        int row = t >> 1, half = t & 1;
        int pl = row >> 6, q = row & 63;
        #pragma unroll
        for (int j = 0; j < 4; ++j) {
            int d = half * 4 + j;
            int sct = d ^ (row & 7);
            __hip_bfloat16 hv[8];
            #pragma unroll
            for (int e = 0; e < 8; ++e) {
                int k = sct * 8 + e;
                float v = 0.f;
                if (k < 48) {
                    int c = k >> 4, r = (k >> 2) & 3, s4 = k & 3;
                    int y = 2 * (p0g + pl) + r - 1;
                    int xg = 2 * q + s4 - 1;
                    if (((unsigned)y < 128u) && ((unsigned)xg < 128u)) {
                        int wrow = c * 6 + 2 * pl + r;
                        v = *(const float*)&smem[32768 + (wrow << 9) + (xg << 2)];
                    }
                }
                hv[e] = __float2bfloat16(v);
            }
            *(bf16x8*)&smem[(row << 7) + d * 16] = *(bf16x8*)hv;
        }
    }
    __syncthreads();

    f32x4 acc[4][4];
    #pragma unroll
    for (int mi = 0; mi < 4; ++mi)
        #pragma unroll
        for (int ni = 0; ni < 4; ++ni) acc[mi][ni] = (f32x4){0.f, 0.f, 0.f, 0.f};

    #pragma unroll
    for (int ks = 0; ks < 2; ++ks) {
        bf16x8 av[4], bv[4];
        #pragma unroll
        for (int mi = 0; mi < 4; ++mi)
            av[mi] = *(const bf16x8*)&smem[fragoff64((wr << 6) + (mi << 4) + (lane & 15), ks, lane)];
        #pragma unroll
        for (int ni = 0; ni < 4; ++ni)
            bv[ni] = *(const bf16x8*)&smem[16384 + fragoff64((wc << 6) + (ni << 4) + (lane & 15), ks, lane)];
        #pragma unroll
        for (int mi = 0; mi < 4; ++mi)
            #pragma unroll
            for (int ni = 0; ni < 4; ++ni)
                acc[mi][ni] = __builtin_amdgcn_mfma_f32_16x16x32_bf16(av[mi], bv[ni], acc[mi][ni], 0, 0, 0);
    }

    int rg = (lane >> 4) << 2;
    #pragma unroll
    for (int mi = 0; mi < 4; ++mi)
        #pragma unroll
        for (int ni = 0; ni < 4; ++ni) {
            int o = (wc << 6) + (ni << 4) + (lane & 15);
            float bias = b1[o];
            #pragma unroll
            for (int j = 0; j < 4; ++j) {
                int rowg = posbase + (wr << 6) + (mi << 4) + rg + j;
                int n = rowg >> 12, p = (rowg >> 6) & 63, q = rowg & 63;
                float v = acc[mi][ni][j] + bias;
                v = v > 0.f ? v : 0.f;
                hb[((n * 66 + p + 1) * 66 + q + 1) * 128 + o] = __float2bfloat16(v);
            }
        }
}

// ---- conv2 + VQ fused, prefetch-dbuf.  M=64, BK=64, 32 steps, 1 barrier/step ----
__global__ __launch_bounds__(256) void k_conv2vq(
    const __hip_bfloat16* __restrict__ hb, const __hip_bfloat16* __restrict__ w2p,
    const float* __restrict__ b2, const __hip_bfloat16* __restrict__ Ep,
    const float* __restrict__ s2, __hip_bfloat16* __restrict__ dq)
{
    __shared__ char smem[49152];                // buf b at b*24576: A 8K | B 16K
    int t = threadIdx.x, lane = t & 63, w = t >> 6;
    int bid0 = blockIdx.x;                      // 512
    int bid = ((bid0 & 7) << 6) | (bid0 >> 3);  // XCD swizzle
    int posbase = bid << 6;
    int n = posbase >> 10, p0 = (posbase >> 5) & 31;

    int aoff[2];
    #pragma unroll
    for (int i = 0; i < 2; ++i) {
        int r = ((w << 1) + i) * 8 + (lane >> 3);
        int slot = lane & 7;
        int p = p0 + (r >> 5), q = r & 31;
        aoff[i] = (((n * 66 + 2 * p) * 66 + 2 * q) << 7) + ((slot ^ (r & 7)) << 3);
    }
    int boff[4];
    #pragma unroll
    for (int i = 0; i < 4; ++i) {
        int o = ((w << 2) + i) * 8 + (lane >> 3);
        int slot = lane & 7;
        boff[i] = (o << 7) + ((slot ^ (o & 7)) << 3);
    }

#define C2_STAGE(STEP, BASE) { \
    int rs_ = (STEP) >> 1, ch_ = (STEP) & 1; \
    int aadd_ = ((((rs_ >> 2) * 66) + (rs_ & 3)) << 7) + (ch_ << 6); \
    int badd_ = (rs_ << 14) + (ch_ << 6); \
    _Pragma("unroll") \
    for (int i = 0; i < 2; ++i) \
        gload16(hb + aoff[i] + aadd_, &smem[(BASE) + (((w << 1) + i) << 10)]); \
    _Pragma("unroll") \
    for (int i = 0; i < 4; ++i) \
        gload16(w2p + boff[i] + badd_, &smem[(BASE) + 8192 + (((w << 2) + i) << 10)]); }

    f32x4 acc[4][2];
    #pragma unroll
    for (int mi = 0; mi < 4; ++mi)
        #pragma unroll
        for (int ni = 0; ni < 2; ++ni) acc[mi][ni] = (f32x4){0.f, 0.f, 0.f, 0.f};

    C2_STAGE(0, 0);
    __syncthreads();
    for (int step = 0; step < 32; ++step) {
        int cb = (step & 1) * 24576;
        if (step < 31) C2_STAGE(step + 1, ((step + 1) & 1) * 24576);
        #pragma unroll
        for (int ks = 0; ks < 2; ++ks) {
            bf16x8 av[4], bv[2];
            #pragma unroll
            for (int mi = 0; mi < 4; ++mi)
                av[mi] = *(const bf16x8*)&smem[cb + fragoff64((mi << 4) + (lane & 15), ks, lane)];
            #pragma unroll
            for (int ni = 0; ni < 2; ++ni)
                bv[ni] = *(const bf16x8*)&smem[cb + 8192 + fragoff64((w << 5) + (ni << 4) + (lane & 15), ks, lane)];
            #pragma unroll
            for (int mi = 0; mi < 4; ++mi)
                #pragma unroll
                for (int ni = 0; ni < 2; ++ni)
                    acc[mi][ni] = __builtin_amdgcn_mfma_f32_16x16x32_bf16(av[mi], bv[ni], acc[mi][ni], 0, 0, 0);
        }
        __syncthreads();
    }

#define VQ_STAGE(CHUNK, BASE) { \
    _Pragma("unroll") \
    for (int i = 0; i < 4; ++i) { \
        int kl_ = (((w << 2) + i) << 2) + (lane >> 4); \
        gload16(Ep + ((((CHUNK) << 6) + kl_) << 7) + (((lane & 15) ^ (kl_ & 7)) << 3), \
                &smem[(BASE) + (((w << 2) + i) << 10)]); \
    } }

    // write z (bias + bf16) into LDS [64 r][128 c] at [0,16K); prefetch E chunk 0
    {
        int rg = (lane >> 4) << 2;
        #pragma unroll
        for (int mi = 0; mi < 4; ++mi)
            #pragma unroll
            for (int ni = 0; ni < 2; ++ni) {
                int o = (w << 5) + (ni << 4) + (lane & 15);
                float bias = b2[o];
                #pragma unroll
                for (int j = 0; j < 4; ++j) {
                    int r = (mi << 4) + rg + j;
                    int byteoff = (r << 8) + (((((o >> 3) ^ (r & 7))) << 4) | ((o & 7) << 1));
                    __hip_bfloat16 hv = __float2bfloat16(acc[mi][ni][j] + bias);
                    *(__hip_bfloat16*)&smem[byteoff] = hv;
                }
            }
    }
    VQ_STAGE(0, 16384);
    __syncthreads();

    float bvv[4][4];
    int   bii[4][4];
    #pragma unroll
    for (int mi = 0; mi < 4; ++mi)
        #pragma unroll
        for (int j = 0; j < 4; ++j) { bvv[mi][j] = 3.4e38f; bii[mi][j] = 0; }

    for (int chunk = 0; chunk < 8; ++chunk) {
        int eb = 16384 + ((chunk & 1) << 14);
        if (chunk < 7) VQ_STAGE(chunk + 1, 16384 + (((chunk + 1) & 1) << 14));
        f32x4 a2[4];
        #pragma unroll
        for (int mi = 0; mi < 4; ++mi) a2[mi] = (f32x4){0.f, 0.f, 0.f, 0.f};
        #pragma unroll
        for (int ks = 0; ks < 4; ++ks) {
            bf16x8 av[4], bv;
            #pragma unroll
            for (int mi = 0; mi < 4; ++mi)
                av[mi] = *(const bf16x8*)&smem[fragoff((mi << 4) + (lane & 15), ks, lane)];
            bv = *(const bf16x8*)&smem[eb + fragoff((w << 4) + (lane & 15), ks, lane)];
            #pragma unroll
            for (int mi = 0; mi < 4; ++mi)
                a2[mi] = __builtin_amdgcn_mfma_f32_16x16x32_bf16(av[mi], bv, a2[mi], 0, 0, 0);
        }
        int kg = (chunk << 6) + (w << 4) + (lane & 15);
        float s2v = s2[kg];
        #pragma unroll
        for (int mi = 0; mi < 4; ++mi)
            #pragma unroll
            for (int j = 0; j < 4; ++j) {
                float sc = s2v - 2.f * a2[mi][j];
                if (sc < bvv[mi][j]) { bvv[mi][j] = sc; bii[mi][j] = kg; }
            }
        __syncthreads();
    }

    float* redv  = (float*)&smem[16384];
    int*   redi  = (int*)&smem[16384 + 1024];
    int*   idx_l = (int*)&smem[16384 + 2048];
    #pragma unroll
    for (int mi = 0; mi < 4; ++mi)
        #pragma unroll
        for (int j = 0; j < 4; ++j) {
            float v = bvv[mi][j];
            int   ix = bii[mi][j];
            #pragma unroll
            for (int m = 1; m < 16; m <<= 1) {
                float ov = __shfl_xor(v, m, 64);
                int   oi = __shfl_xor(ix, m, 64);
                if (ov < v || (ov == v && oi < ix)) { v = ov; ix = oi; }
            }
            if ((lane & 15) == 0) {
                int r = (mi << 4) + ((lane >> 4) << 2) + j;
                redv[(r << 2) + w] = v;
                redi[(r << 2) + w] = ix;
            }
        }
    __syncthreads();
    if (t < 64) {
        float bv_ = redv[t << 2];
        int   bi_ = redi[t << 2];
        #pragma unroll
        for (int w2 = 1; w2 < 4; ++w2) {
            float ov = redv[(t << 2) + w2];
            int   oi = redi[(t << 2) + w2];
            if (ov < bv_ || (ov == bv_ && oi < bi_)) { bv_ = ov; bi_ = oi; }
        }
        idx_l[t] = bi_;
    }
    __syncthreads();

    #pragma unroll
    for (int i = 0; i < 4; ++i) {
        int idx2 = (w << 2) + i;
        int r = (idx2 << 2) + (lane >> 4);
        int krow = idx_l[r];
        gload16(Ep + ((krow << 7) + ((lane & 15) << 3)), &smem[idx2 << 10]);
    }
    __syncthreads();

    int cd0 = (posbase >> 3) & 127;
    const unsigned short* eb2p = (const unsigned short*)smem;
    #pragma unroll
    for (int k2 = 0; k2 < 4; ++k2) {
        int sp = (k2 << 8) + t;
        int hi = sp >> 7, lo = sp & 127;
        int y = sp >> 5, xx = sp & 31;
        unsigned short vals[8];
        #pragma unroll
        for (int ci = 0; ci < 8; ++ci)
            vals[ci] = eb2p[(((ci << 3) + hi) << 7) + lo];
        __hip_bfloat16* dst = dq + ((n * 34 + y + 1) * 34 + (xx + 1)) * 128 + cd0;
        *(bf16x8*)dst = *(bf16x8*)vals;
    }
}

// ---- deconv1, prefetch-dbuf: M=128, BK=64, 8 steps, 1 barrier/step ----
__global__ __launch_bounds__(256) void k_deconv1(
    const __hip_bfloat16* __restrict__ dq, const __hip_bfloat16* __restrict__ w1p,
    const float* __restrict__ b1, __hip_bfloat16* __restrict__ g)
{
    __shared__ char smem[65536];                // buf b at b*32768: A 16K | B 16K
    int t = threadIdx.x, lane = t & 63, w = t >> 6;
    int wr = w >> 1, wc = w & 1;
    int bid0 = blockIdx.x;                      // 1024
    int bid = ((bid0 & 7) << 7) | (bid0 >> 3);  // XCD swizzle
    int ag = bid & 7, qe = (bid >> 3) & 1, pe = (bid >> 4) & 1, n = bid >> 5;

    int aoff[4], boff[4];
    #pragma unroll
    for (int i = 0; i < 4; ++i) {
        int r = ((w << 2) + i) * 8 + (lane >> 3);
        int slot = lane & 7;
        int a = (ag << 2) + (r >> 5), b = r & 31;
        aoff[i] = (((n * 34 + (a + pe)) * 34 + (b + qe)) << 7) + ((slot ^ (r & 7)) << 3);
        boff[i] = (r << 7) + ((slot ^ (r & 7)) << 3);
    }
    int mbase = (pe << 3) | (qe << 2);

#define D1_STAGE(STEP, BASE) { \
    int tu_ = (STEP) >> 1, ch_ = (STEP) & 1; \
    int tt_ = tu_ >> 1, u_ = tu_ & 1; \
    int aadd_ = ((tt_ * 34 + u_) << 7) + (ch_ << 6); \
    int badd_ = ((mbase + tu_) << 14) + (ch_ << 6); \
    _Pragma("unroll") \
    for (int i = 0; i < 4; ++i) { \
        gload16(dq + aoff[i] + aadd_, &smem[(BASE) + (((w << 2) + i) << 10)]); \
        gload16(w1p + boff[i] + badd_, &smem[(BASE) + 16384 + (((w << 2) + i) << 10)]); \
    } }

    f32x4 acc[4][4];
    #pragma unroll
    for (int mi = 0; mi < 4; ++mi)
        #pragma unroll
        for (int ni = 0; ni < 4; ++ni) acc[mi][ni] = (f32x4){0.f, 0.f, 0.f, 0.f};

    D1_STAGE(0, 0);
    __syncthreads();
    for (int step = 0; step < 8; ++step) {
        int cb = (step & 1) * 32768;
        if (step < 7) D1_STAGE(step + 1, ((step + 1) & 1) * 32768);
        #pragma unroll
        for (int ks = 0; ks < 2; ++ks) {
            bf16x8 av[4], bv[4];
            #pragma unroll
            for (int mi = 0; mi < 4; ++mi)
                av[mi] = *(const bf16x8*)&smem[cb + fragoff64((wr << 6) + (mi << 4) + (lane & 15), ks, lane)];
            #pragma unroll
            for (int ni = 0; ni < 4; ++ni)
                bv[ni] = *(const bf16x8*)&smem[cb + 16384 + fragoff64((wc << 6) + (ni << 4) + (lane & 15), ks, lane)];
            #pragma unroll
            for (int mi = 0; mi < 4; ++mi)
                #pragma unroll
                for (int ni = 0; ni < 4; ++ni)
                    acc[mi][ni] = __builtin_amdgcn_mfma_f32_16x16x32_bf16(av[mi], bv[ni], acc[mi][ni], 0, 0, 0);
        }
        __syncthreads();
    }

    int rg = (lane >> 4) << 2;
    #pragma unroll
    for (int mi = 0; mi < 4; ++mi)
        #pragma unroll
        for (int ni = 0; ni < 4; ++ni) {
            int o = (wc << 6) + (ni << 4) + (lane & 15);
            float bias = b1[o];
            #pragma unroll
            for (int j = 0; j < 4; ++j) {
                int row = (wr << 6) + (mi << 4) + rg + j;
                int a = (ag << 2) + (row >> 5), b = row & 31;
                int y = 2 * a + pe, xx2 = 2 * b + qe;
                float v = acc[mi][ni][j] + bias;
                v = v > 0.f ? v : 0.f;
                g[((n * 66 + y + 1) * 66 + xx2 + 1) * 128 + o] = __float2bfloat16(v);
            }
        }
}

// ---- deconv2, 9-neighbor, prefetch-dbuf: BK=64, 18 steps, 1 barrier/step ----
__global__ __launch_bounds__(256) void k_deconv2g(
    const __hip_bfloat16* __restrict__ g, const __hip_bfloat16* __restrict__ w2db9,
    const float* __restrict__ b2, float* __restrict__ out)
{
    __shared__ char smem[36864];                // buf b at b*18432: A 16K | B 2K
    int t = threadIdx.x, lane = t & 63, w = t >> 6;
    int bid0 = blockIdx.x;                      // 1024
    int bid = ((bid0 & 7) << 7) | (bid0 >> 3);  // XCD swizzle
    int atile = bid & 31, n = bid >> 5;
    int a0 = atile << 1;

    int aoff[4];
    #pragma unroll
    for (int i = 0; i < 4; ++i) {
        int r = ((w << 2) + i) * 8 + (lane >> 3);
        int al = r >> 6, b = r & 63;
        aoff[i] = (((n * 66 + (a0 + al)) * 66 + b) << 7) + (((lane & 7) ^ (r & 7)) << 3);
    }

#define D2_STAGE(STEP, BASE) { \
    int de_ = (STEP) >> 1, ch_ = (STEP) & 1; \
    int dy_ = de_ / 3, dx_ = de_ - dy_ * 3; \
    int aadd_ = ((dy_ * 66 + dx_) << 7) + (ch_ << 6); \
    _Pragma("unroll") \
    for (int i = 0; i < 4; ++i) \
        gload16(g + aoff[i] + aadd_, &smem[(BASE) + (((w << 2) + i) << 10)]); \
    if (w < 2) { \
        int kl_ = (w << 3) + (lane >> 3); \
        gload16(w2db9 + (de_ << 11) + (kl_ << 7) + (ch_ << 6) + (((lane & 7) ^ (kl_ & 7)) << 3), \
                &smem[(BASE) + 16384 + (w << 10)]); \
    } }

    f32x4 acc[2];
    acc[0] = (f32x4){0.f, 0.f, 0.f, 0.f};
    acc[1] = (f32x4){0.f, 0.f, 0.f, 0.f};

    D2_STAGE(0, 0);
    __syncthreads();
    for (int step = 0; step < 18; ++step) {
        int cb = (step & 1) * 18432;
        if (step < 17) D2_STAGE(step + 1, ((step + 1) & 1) * 18432);
        #pragma unroll
        for (int ks = 0; ks < 2; ++ks) {
            bf16x8 av[2], bv;
            #pragma unroll
            for (int mi = 0; mi < 2; ++mi)
                av[mi] = *(const bf16x8*)&smem[cb + fragoff64((w << 5) + (mi << 4) + (lane & 15), ks, lane)];
            bv = *(const bf16x8*)&smem[cb + 16384 + fragoff64(lane & 15, ks, lane)];
            #pragma unroll
            for (int mi = 0; mi < 2; ++mi)
                acc[mi] = __builtin_amdgcn_mfma_f32_16x16x32_bf16(av[mi], bv, acc[mi], 0, 0, 0);
        }
        __syncthreads();
    }

    int rg = (lane >> 4) << 2;
    int col = lane & 15, o = col & 3, pq = col >> 2;
    if (o < 3) {
        int pe = pq >> 1, qe = pq & 1;
        float bias = b2[o];
        #pragma unroll
        for (int mi = 0; mi < 2; ++mi)
            #pragma unroll
            for (int j = 0; j < 4; ++j) {
                int row = (w << 5) + (mi << 4) + rg + j;
                int y = 2 * (a0 + (row >> 6)) + pe;
                int x = 2 * (row & 63) + qe;
                float v = acc[mi][j] + bias;
                out[((n * 3 + o) * 128 + y) * 128 + x] = 1.f / (1.f + expf(-v));
            }
    }
}

extern "C" void kernel_launch(void* const* d_in, const int* in_sizes, int n_in,
                              void* d_out, int out_size, void* d_ws, size_t ws_size,
                              hipStream_t stream) {
    const float* x   = (const float*)d_in[0];
    const float* ew1 = (const float*)d_in[1];
    const float* eb1 = (const float*)d_in[2];
    const float* ew2 = (const float*)d_in[3];
    const float* eb2 = (const float*)d_in[4];
    const float* E   = (const float*)d_in[5];
    const float* dw1 = (const float*)d_in[6];
    const float* db1 = (const float*)d_in[7];
    const float* dw2 = (const float*)d_in[8];
    const float* db2 = (const float*)d_in[9];
    float* out = (float*)d_out;

    char* W = (char*)d_ws;
    __hip_bfloat16* hb    = (__hip_bfloat16*)(W + 0);
    __hip_bfloat16* g     = (__hip_bfloat16*)(W + 0);  // union: hb dead after conv2
    __hip_bfloat16* dq    = (__hip_bfloat16*)(W + 75497472);
    __hip_bfloat16* w2p   = (__hip_bfloat16*)(W + 84967424);
    __hip_bfloat16* w1p   = (__hip_bfloat16*)(W + 85491712);
    __hip_bfloat16* Ep    = (__hip_bfloat16*)(W + 86016000);
    __hip_bfloat16* w2db9 = (__hip_bfloat16*)(W + 86147072);
    float*          s2    = (float*)(W + 86184192);
    __hip_bfloat16* w1b   = (__hip_bfloat16*)(W + 86186240);

    k_init    <<<3194, 256, 0, stream>>>(ew1, ew2, E, dw1, dw2,
                                         hb, w2p, w1p, Ep, w1b, w2db9, dq, s2);
    k_conv1g  <<<1024, 256, 0, stream>>>(x, w1b, eb1, hb);
    k_conv2vq <<<512,  256, 0, stream>>>(hb, w2p, eb2, Ep, s2, dq);
    k_deconv1 <<<1024, 256, 0, stream>>>(dq, w1p, db1, g);
    k_deconv2g<<<1024, 256, 0, stream>>>(g, w2db9, db2, out);
}